// Round 18
// baseline (172.133 us; speedup 1.0000x reference)
//
#include <hip/hip_runtime.h>
#include <hip/hip_fp16.h>
#include <math.h>

#define N_TOKENS 16384
#define D_MODEL  2048
#define NE       64
#define TOPK     8

typedef float    f32x4 __attribute__((ext_vector_type(4)));
typedef _Float16 f16x8 __attribute__((ext_vector_type(8)));
typedef short    s16x8 __attribute__((ext_vector_type(8)));

#define LDSROW 34                  // shorts per x-row (32 data + 2 pad; conflict-free per R14-R17)
#define PLANE  (16 * LDSROW)       // 544 shorts per split plane
#define CH_BUF (2 * PLANE)         // one chunk buffer (h+m planes) = 1088 shorts
#define NBUF   8                   // 8 chunk buffers -> write 4 chunks ahead of read
#define WSCL   512.0f              // B pre-scale (keeps Bm out of f16 denormals)
#define XSCL   1024.0f             // x pre-scale (keeps Am out of f16 denormals)
#define UNSCL  (1.0 / (1024.0 * 512.0))   // exact 2^-19

// Pre-pass v2 (coalesced reads): thread = (k, j). Wave reads 64 consecutive
// floats of one W row (coalesced); writes 2 scattered shorts (L2-absorbed).
// Layout identical to R16/R17: BF[((c*8+ct)*2+s)*64 + l][e8],
// l = l_hi*16 + l_lo, where c=k>>5, kk=k&31, l_hi=kk>>3, e8=kk&7,
// ct=j>>4, l_lo=j&15.
__global__ __launch_bounds__(256)
void bf_build(const float* __restrict__ Wg, const float* __restrict__ Wn,
              short* __restrict__ BFs) {
    const int id = blockIdx.x * 256 + threadIdx.x;   // 0..262143
    const int k  = id >> 7;        // 0..2047
    const int j  = id & 127;       // 0..127
    const float w = (j < NE) ? Wg[(size_t)k * NE + j] : Wn[(size_t)k * NE + (j - NE)];
    const float v = w * WSCL;
    __half h = __float2half(v);                        // RNE
    __half m = __float2half(v - __half2float(h));      // exact residual (Sterbenz)
    const int c = k >> 5, kk = k & 31;
    const int l_hi = kk >> 3, e8 = kk & 7;
    const int ct = j >> 4, l_lo = j & 15;
    const size_t base = ((size_t)((c * 8 + ct) * 2) * 64 + l_hi * 16 + l_lo) * 8 + e8;
    BFs[base]       = __half_as_short(h);
    BFs[base + 512] = __half_as_short(m);   // s=1 plane is +64 words = +512 shorts
}

// ---------------- Kernel A: pure GEMM (R17 structure, deeper pipeline) ----------------
__global__ __launch_bounds__(512, 8)
void router_gemm(const float* __restrict__ x, const s16x8* __restrict__ BF,
                 float* __restrict__ dots)    // [N_TOKENS][128] fp32
{
    __shared__ short xsp[NBUF * CH_BUF];     // 17408 B: 8-deep chunk ring

    const int tid  = threadIdx.x;
    const int lane = tid & 63;
    const int wv   = tid >> 6;            // wave id = ctile 0..7 (16 cols each)
    const int row0 = blockIdx.x * 16;

    // ---- convert mapping: one float per thread per 32-k chunk ----
    const int crow = tid >> 5;            // 0..15
    const int ck   = tid & 31;            // 0..31
    const float* xp = x + (size_t)(row0 + crow) * D_MODEL + ck;
    const int cbase = crow * LDSROW + ck;

    auto convert_store = [&](float vf, int c) {
        float v  = vf * XSCL;                          // exact pow2 scale
        __half h = __float2half(v);                    // RNE
        float  r = v - __half2float(h);                // exact (Sterbenz)
        __half m = __float2half(r);
        short* xb = xsp + (c & (NBUF - 1)) * CH_BUF;
        xb[cbase]         = __half_as_short(h);
        xb[cbase + PLANE] = __half_as_short(m);
    };

    // ---- wave MFMA state ----
    const int abase = (lane & 15) * LDSROW + (lane >> 4) * 8;
    const f16x8* bfp = (const f16x8*)BF + lane;

    auto loadB = [&](int c, f16x8& bh, f16x8& bm) {
        const f16x8* p = bfp + (size_t)((c * 8 + wv) * 2) * 64;
        bh = p[0];
        bm = p[64];
    };

    f32x4 Ca = {0.f,0.f,0.f,0.f}, Cb = Ca;
    double facc[4] = {0.0, 0.0, 0.0, 0.0};

    auto do_chunk = [&](f16x8 Bh, f16x8 Bm, int c) {
        const short* xb = xsp + (c & (NBUF - 1)) * CH_BUF;
        f16x8 Ah = *(const f16x8*)&xb[abase];
        f16x8 Am = *(const f16x8*)&xb[abase + PLANE];
        Ca = __builtin_amdgcn_mfma_f32_16x16x32_f16(Am, Bh, Ca, 0, 0, 0); // mh (small first)
        Cb = __builtin_amdgcn_mfma_f32_16x16x32_f16(Ah, Bm, Cb, 0, 0, 0); // hm
        Ca = __builtin_amdgcn_mfma_f32_16x16x32_f16(Ah, Bh, Ca, 0, 0, 0); // hh
    };

    #define CONVOY_BARRIER() do {                                   \
        asm volatile("s_waitcnt lgkmcnt(0)" ::: "memory");          \
        __builtin_amdgcn_s_barrier();                               \
        __builtin_amdgcn_sched_barrier(0);                          \
    } while (0)

    // ---- prologue: chunks 0..3 converted; u-ring = x(4..7); B(0),B(1) ----
    f16x8 BAh, BAm, BBh, BBm;
    convert_store(xp[0 * 32], 0);
    convert_store(xp[1 * 32], 1);
    convert_store(xp[2 * 32], 2);
    convert_store(xp[3 * 32], 3);
    float u0 = xp[4 * 32], u1 = xp[5 * 32], u2 = xp[6 * 32], u3 = xp[7 * 32];
    loadB(0, BAh, BAm);
    loadB(1, BBh, BBm);
    CONVOY_BARRIER();

    // ---- main loop: 32 periods x 2 chunks, one barrier per period.
    // Invariant at top of period p (c = 2p): slots hold chunks c..c+3;
    // BA/BB = B(c),B(c+1); u-half (p&1) = x(c+4),x(c+5) [consumed this period];
    // other u-half = x(c+6),x(c+7) [in flight, consumed next period].
    // x issue->consume distance = 2 periods (~>=700cy >= HBM latency);
    // converts land 2 barriers before their reader.
    #pragma unroll 1
    for (int p = 0; p < 32; ++p) {
        const int c = 2 * p;
        do_chunk(BAh, BAm, c);
        if (c + 2 < 64) loadB(c + 2, BAh, BAm);   // in flight across the barrier
        do_chunk(BBh, BBm, c + 1);
        if (c + 3 < 64) loadB(c + 3, BBh, BBm);
        if ((p & 1) == 0) {
            if (c + 4 < 64) { convert_store(u0, c + 4); convert_store(u1, c + 5); }
            if (c + 8 < 64) { u0 = xp[(c + 8) * 32]; u1 = xp[(c + 9) * 32]; }
        } else {
            if (c + 4 < 64) { convert_store(u2, c + 4); convert_store(u3, c + 5); }
            if (c + 8 < 64) { u2 = xp[(c + 8) * 32]; u3 = xp[(c + 9) * 32]; }
        }
        #pragma unroll
        for (int j = 0; j < 4; ++j) {             // fp64 fold every 64 k (same cadence R12-R17)
            facc[j] += (double)Ca[j] + (double)Cb[j];
            Ca[j] = 0.f; Cb[j] = 0.f;
        }
        CONVOY_BARRIER();
    }

    // ---- write fp32 dots (unscale by exact 2^-19) ----
    const int ocol = wv * 16 + (lane & 15);
    #pragma unroll
    for (int j = 0; j < 4; ++j)
        dots[(size_t)(row0 + (lane >> 4) * 4 + j) * 128 + ocol]
            = (float)(facc[j] * UNSCL);
}

// ---------------- Kernel B: softplus + noise + top-8 + sparse softmax ----------------
// Byte-identical to R17 (proven): one wave per token, fp64 selection path.
__global__ __launch_bounds__(512)
void router_topk(const float* __restrict__ dots, const float* __restrict__ eps,
                 const float* __restrict__ bg, const float* __restrict__ bn,
                 float* __restrict__ out_probs, float* __restrict__ out_idx)
{
    const int tid  = threadIdx.x;
    const int lane = tid & 63;
    const int wv   = tid >> 6;
    const int tok  = blockIdx.x * 8 + wv;

    const double logit = (double)dots[(size_t)tok * 128 + lane]      + (double)bg[lane];
    const double nvv   = (double)dots[(size_t)tok * 128 + 64 + lane] + (double)bn[lane];
    const double sp    = (nvv > 0.0) ? (nvv + log1p(exp(-nvv))) : log1p(exp(nvv));
    const double noisy = logit + (double)eps[(size_t)tok * NE + lane] * sp;

    // iterative top-8; tie-break: higher value, then lower index (lax.top_k)
    double cur = noisy;
    double m = 0.0, sum = 0.0;
    int    sel = 0;
    float  my_idx = 0.0f;
    #pragma unroll
    for (int rk = 0; rk < TOPK; ++rk) {
        double bv = cur;
        int    bi = lane;
        #pragma unroll
        for (int off = 32; off >= 1; off >>= 1) {
            double ov = __shfl_xor(bv, off);
            int    oi = __shfl_xor(bi, off);
            if (ov > bv || (ov == bv && oi < bi)) { bv = ov; bi = oi; }
        }
        if (rk == 0) m = bv;
        sum += exp(bv - m);
        if (lane == bi) { sel = 1; cur = -INFINITY; }
        if (lane == rk) my_idx = (float)bi;
    }

    out_probs[(size_t)tok * NE + lane] = (float)(sel ? exp(noisy - m) / sum : 0.0);
    if (lane < TOPK) out_idx[(size_t)tok * TOPK + lane] = my_idx;
}

extern "C" void kernel_launch(void* const* d_in, const int* in_sizes, int n_in,
                              void* d_out, int out_size, void* d_ws, size_t ws_size,
                              hipStream_t stream) {
    const float* x   = (const float*)d_in[0];
    const float* eps = (const float*)d_in[1];
    const float* Wg  = (const float*)d_in[2];
    const float* bg  = (const float*)d_in[3];
    const float* Wn  = (const float*)d_in[4];
    const float* bn  = (const float*)d_in[5];

    float* out_probs = (float*)d_out;                              // [N, E]
    float* out_idx   = (float*)d_out + (size_t)N_TOKENS * NE;      // [N, K]

    // d_ws layout: BF fragments (1 MB) | dots fp32 [16384][128] (8 MB)
    s16x8* BF   = (s16x8*)d_ws;
    float* dots = (float*)((char*)d_ws + (size_t)65536 * 16);

    bf_build<<<dim3(1024), dim3(256), 0, stream>>>(Wg, Wn, (short*)BF);

    router_gemm<<<dim3(N_TOKENS / 16), dim3(512), 0, stream>>>(x, BF, dots);

    router_topk<<<dim3(N_TOKENS / 8), dim3(512), 0, stream>>>(
        dots, eps, bg, bn, out_probs, out_idx);
}

// Round 19
// 172.032 us; speedup vs baseline: 1.0006x; 1.0006x over previous
//
#include <hip/hip_runtime.h>
#include <hip/hip_fp16.h>
#include <math.h>

#define N_TOKENS 16384
#define D_MODEL  2048
#define NE       64
#define TOPK     8

typedef float    f32x4 __attribute__((ext_vector_type(4)));
typedef _Float16 f16x8 __attribute__((ext_vector_type(8)));
typedef short    s16x8 __attribute__((ext_vector_type(8)));

#define LDSROW 34                  // shorts per x-row (32 data + 2 pad; conflict-free per R14-R17)
#define PLANE  (16 * LDSROW)       // 544 shorts per split plane
#define CH_BUF (2 * PLANE)         // one chunk buffer (h+m planes) = 1088 shorts
#define NBUF   8                   // 8 chunk buffers -> write 4 chunks ahead of read
#define WSCL   512.0f              // B pre-scale (keeps Bm out of f16 denormals)
#define XSCL   1024.0f             // x pre-scale (keeps Am out of f16 denormals)
#define UNSCL  (1.0 / (1024.0 * 512.0))   // exact 2^-19

// Pre-pass v2 (coalesced reads): thread = (k, j). Wave reads 64 consecutive
// floats of one W row (coalesced); writes 2 scattered shorts (L2-absorbed).
// Layout identical to R16/R17: BF[((c*8+ct)*2+s)*64 + l][e8],
// l = l_hi*16 + l_lo, where c=k>>5, kk=k&31, l_hi=kk>>3, e8=kk&7,
// ct=j>>4, l_lo=j&15.
__global__ __launch_bounds__(256)
void bf_build(const float* __restrict__ Wg, const float* __restrict__ Wn,
              short* __restrict__ BFs) {
    const int id = blockIdx.x * 256 + threadIdx.x;   // 0..262143
    const int k  = id >> 7;        // 0..2047
    const int j  = id & 127;       // 0..127
    const float w = (j < NE) ? Wg[(size_t)k * NE + j] : Wn[(size_t)k * NE + (j - NE)];
    const float v = w * WSCL;
    __half h = __float2half(v);                        // RNE
    __half m = __float2half(v - __half2float(h));      // exact residual (Sterbenz)
    const int c = k >> 5, kk = k & 31;
    const int l_hi = kk >> 3, e8 = kk & 7;
    const int ct = j >> 4, l_lo = j & 15;
    const size_t base = ((size_t)((c * 8 + ct) * 2) * 64 + l_hi * 16 + l_lo) * 8 + e8;
    BFs[base]       = __half_as_short(h);
    BFs[base + 512] = __half_as_short(m);   // s=1 plane is +64 words = +512 shorts
}

// ---------------- Kernel A: pure GEMM (R17 structure, deeper pipeline) ----------------
__global__ __launch_bounds__(512, 8)
void router_gemm(const float* __restrict__ x, const s16x8* __restrict__ BF,
                 float* __restrict__ dots)    // [N_TOKENS][128] fp32
{
    __shared__ short xsp[NBUF * CH_BUF];     // 17408 B: 8-deep chunk ring

    const int tid  = threadIdx.x;
    const int lane = tid & 63;
    const int wv   = tid >> 6;            // wave id = ctile 0..7 (16 cols each)
    const int row0 = blockIdx.x * 16;

    // ---- convert mapping: one float per thread per 32-k chunk ----
    const int crow = tid >> 5;            // 0..15
    const int ck   = tid & 31;            // 0..31
    const float* xp = x + (size_t)(row0 + crow) * D_MODEL + ck;
    const int cbase = crow * LDSROW + ck;

    auto convert_store = [&](float vf, int c) {
        float v  = vf * XSCL;                          // exact pow2 scale
        __half h = __float2half(v);                    // RNE
        float  r = v - __half2float(h);                // exact (Sterbenz)
        __half m = __float2half(r);
        short* xb = xsp + (c & (NBUF - 1)) * CH_BUF;
        xb[cbase]         = __half_as_short(h);
        xb[cbase + PLANE] = __half_as_short(m);
    };

    // ---- wave MFMA state ----
    const int abase = (lane & 15) * LDSROW + (lane >> 4) * 8;
    const f16x8* bfp = (const f16x8*)BF + lane;

    auto loadB = [&](int c, f16x8& bh, f16x8& bm) {
        const f16x8* p = bfp + (size_t)((c * 8 + wv) * 2) * 64;
        bh = p[0];
        bm = p[64];
    };

    f32x4 Ca = {0.f,0.f,0.f,0.f}, Cb = Ca;
    double facc[4] = {0.0, 0.0, 0.0, 0.0};

    auto do_chunk = [&](f16x8 Bh, f16x8 Bm, int c) {
        const short* xb = xsp + (c & (NBUF - 1)) * CH_BUF;
        f16x8 Ah = *(const f16x8*)&xb[abase];
        f16x8 Am = *(const f16x8*)&xb[abase + PLANE];
        Ca = __builtin_amdgcn_mfma_f32_16x16x32_f16(Am, Bh, Ca, 0, 0, 0); // mh (small first)
        Cb = __builtin_amdgcn_mfma_f32_16x16x32_f16(Ah, Bm, Cb, 0, 0, 0); // hm
        Ca = __builtin_amdgcn_mfma_f32_16x16x32_f16(Ah, Bh, Ca, 0, 0, 0); // hh
    };

    #define CONVOY_BARRIER() do {                                   \
        asm volatile("s_waitcnt lgkmcnt(0)" ::: "memory");          \
        __builtin_amdgcn_s_barrier();                               \
        __builtin_amdgcn_sched_barrier(0);                          \
    } while (0)

    // ---- prologue: chunks 0..3 converted; u-ring = x(4..7); B(0),B(1) ----
    f16x8 BAh, BAm, BBh, BBm;
    convert_store(xp[0 * 32], 0);
    convert_store(xp[1 * 32], 1);
    convert_store(xp[2 * 32], 2);
    convert_store(xp[3 * 32], 3);
    float u0 = xp[4 * 32], u1 = xp[5 * 32], u2 = xp[6 * 32], u3 = xp[7 * 32];
    loadB(0, BAh, BAm);
    loadB(1, BBh, BBm);
    CONVOY_BARRIER();

    // ---- main loop: 32 periods x 2 chunks, one barrier per period.
    // Invariant at top of period p (c = 2p): slots hold chunks c..c+3;
    // BA/BB = B(c),B(c+1); u-half (p&1) = x(c+4),x(c+5) [consumed this period];
    // other u-half = x(c+6),x(c+7) [in flight, consumed next period].
    // x issue->consume distance = 2 periods (~>=700cy >= HBM latency);
    // converts land 2 barriers before their reader.
    #pragma unroll 1
    for (int p = 0; p < 32; ++p) {
        const int c = 2 * p;
        do_chunk(BAh, BAm, c);
        if (c + 2 < 64) loadB(c + 2, BAh, BAm);   // in flight across the barrier
        do_chunk(BBh, BBm, c + 1);
        if (c + 3 < 64) loadB(c + 3, BBh, BBm);
        if ((p & 1) == 0) {
            if (c + 4 < 64) { convert_store(u0, c + 4); convert_store(u1, c + 5); }
            if (c + 8 < 64) { u0 = xp[(c + 8) * 32]; u1 = xp[(c + 9) * 32]; }
        } else {
            if (c + 4 < 64) { convert_store(u2, c + 4); convert_store(u3, c + 5); }
            if (c + 8 < 64) { u2 = xp[(c + 8) * 32]; u3 = xp[(c + 9) * 32]; }
        }
        #pragma unroll
        for (int j = 0; j < 4; ++j) {             // fp64 fold every 64 k (same cadence R12-R17)
            facc[j] += (double)Ca[j] + (double)Cb[j];
            Ca[j] = 0.f; Cb[j] = 0.f;
        }
        CONVOY_BARRIER();
    }

    // ---- write fp32 dots (unscale by exact 2^-19) ----
    const int ocol = wv * 16 + (lane & 15);
    #pragma unroll
    for (int j = 0; j < 4; ++j)
        dots[(size_t)(row0 + (lane >> 4) * 4 + j) * 128 + ocol]
            = (float)(facc[j] * UNSCL);
}

// ---------------- Kernel B: softplus + noise + top-8 + sparse softmax ----------------
// Byte-identical to R17 (proven): one wave per token, fp64 selection path.
__global__ __launch_bounds__(512)
void router_topk(const float* __restrict__ dots, const float* __restrict__ eps,
                 const float* __restrict__ bg, const float* __restrict__ bn,
                 float* __restrict__ out_probs, float* __restrict__ out_idx)
{
    const int tid  = threadIdx.x;
    const int lane = tid & 63;
    const int wv   = tid >> 6;
    const int tok  = blockIdx.x * 8 + wv;

    const double logit = (double)dots[(size_t)tok * 128 + lane]      + (double)bg[lane];
    const double nvv   = (double)dots[(size_t)tok * 128 + 64 + lane] + (double)bn[lane];
    const double sp    = (nvv > 0.0) ? (nvv + log1p(exp(-nvv))) : log1p(exp(nvv));
    const double noisy = logit + (double)eps[(size_t)tok * NE + lane] * sp;

    // iterative top-8; tie-break: higher value, then lower index (lax.top_k)
    double cur = noisy;
    double m = 0.0, sum = 0.0;
    int    sel = 0;
    float  my_idx = 0.0f;
    #pragma unroll
    for (int rk = 0; rk < TOPK; ++rk) {
        double bv = cur;
        int    bi = lane;
        #pragma unroll
        for (int off = 32; off >= 1; off >>= 1) {
            double ov = __shfl_xor(bv, off);
            int    oi = __shfl_xor(bi, off);
            if (ov > bv || (ov == bv && oi < bi)) { bv = ov; bi = oi; }
        }
        if (rk == 0) m = bv;
        sum += exp(bv - m);
        if (lane == bi) { sel = 1; cur = -INFINITY; }
        if (lane == rk) my_idx = (float)bi;
    }

    out_probs[(size_t)tok * NE + lane] = (float)(sel ? exp(noisy - m) / sum : 0.0);
    if (lane < TOPK) out_idx[(size_t)tok * TOPK + lane] = my_idx;
}

extern "C" void kernel_launch(void* const* d_in, const int* in_sizes, int n_in,
                              void* d_out, int out_size, void* d_ws, size_t ws_size,
                              hipStream_t stream) {
    const float* x   = (const float*)d_in[0];
    const float* eps = (const float*)d_in[1];
    const float* Wg  = (const float*)d_in[2];
    const float* bg  = (const float*)d_in[3];
    const float* Wn  = (const float*)d_in[4];
    const float* bn  = (const float*)d_in[5];

    float* out_probs = (float*)d_out;                              // [N, E]
    float* out_idx   = (float*)d_out + (size_t)N_TOKENS * NE;      // [N, K]

    // d_ws layout: BF fragments (1 MB) | dots fp32 [16384][128] (8 MB)
    s16x8* BF   = (s16x8*)d_ws;
    float* dots = (float*)((char*)d_ws + (size_t)65536 * 16);

    bf_build<<<dim3(1024), dim3(256), 0, stream>>>(Wg, Wn, (short*)BF);

    router_gemm<<<dim3(N_TOKENS / 16), dim3(512), 0, stream>>>(x, BF, dots);

    router_topk<<<dim3(N_TOKENS / 8), dim3(512), 0, stream>>>(
        dots, eps, bg, bn, out_probs, out_idx);
}